// Round 1
// baseline (653.329 us; speedup 1.0000x reference)
//
#include <hip/hip_runtime.h>
#include <hip/hip_bf16.h>

#define BATCH 8
#define NPTS 2048
#define LATENT 128

// ---------------------------------------------------------------------------
// centroid + centering: one block per batch
// ---------------------------------------------------------------------------
__global__ __launch_bounds__(256) void centroid_kernel(const float* __restrict__ x,
    const float* __restrict__ mask, float* __restrict__ xc) {
  const int b = blockIdx.x;
  const int tid = threadIdx.x;
  const float* xb = x + (size_t)b * NPTS * 3;
  const float* mb = mask + (size_t)b * NPTS;
  float s0 = 0.f, s1 = 0.f, s2 = 0.f, c = 0.f;
  for (int n = tid; n < NPTS; n += 256) {
    float m = mb[n];
    s0 += xb[n * 3 + 0] * m;
    s1 += xb[n * 3 + 1] * m;
    s2 += xb[n * 3 + 2] * m;
    c += m;
  }
  __shared__ float red[4][256];
  red[0][tid] = s0; red[1][tid] = s1; red[2][tid] = s2; red[3][tid] = c;
  __syncthreads();
  for (int off = 128; off > 0; off >>= 1) {
    if (tid < off) {
      red[0][tid] += red[0][tid + off];
      red[1][tid] += red[1][tid + off];
      red[2][tid] += red[2][tid + off];
      red[3][tid] += red[3][tid + off];
    }
    __syncthreads();
  }
  const float cnt = fmaxf(red[3][0], 1.0f);
  const float c0 = red[0][0] / cnt, c1 = red[1][0] / cnt, c2 = red[2][0] / cnt;
  float* ob = xc + (size_t)b * NPTS * 3;
  for (int n = tid; n < NPTS; n += 256) {
    ob[n * 3 + 0] = xb[n * 3 + 0] - c0;
    ob[n * 3 + 1] = xb[n * 3 + 1] - c1;
    ob[n * 3 + 2] = xb[n * 3 + 2] - c2;
  }
}

// ---------------------------------------------------------------------------
// layer-0 aggregation: h == xc (DIN=3). One thread per output row.
// w_ij = exp(-||xc_i - xc_j||^2); out = (sum_j w*h_j) / (sum_j w)
// ---------------------------------------------------------------------------
__global__ __launch_bounds__(256) void agg3_kernel(const float* __restrict__ xc,
    float* __restrict__ hagg) {
  const int b = blockIdx.y;
  const int tid = threadIdx.x;
  const int i = blockIdx.x * 256 + tid;
  const float* xb = xc + (size_t)b * NPTS * 3;
  const float xi0 = xb[i * 3 + 0], xi1 = xb[i * 3 + 1], xi2 = xb[i * 3 + 2];
  float a0 = 0.f, a1 = 0.f, a2 = 0.f, den = 0.f;
  __shared__ float sx[256 * 3];
  for (int j0 = 0; j0 < NPTS; j0 += 256) {
    __syncthreads();
    for (int t = tid; t < 768; t += 256) sx[t] = xb[j0 * 3 + t];
    __syncthreads();
#pragma unroll 4
    for (int jj = 0; jj < 256; jj++) {
      const float h0 = sx[jj * 3 + 0], h1 = sx[jj * 3 + 1], h2 = sx[jj * 3 + 2];
      const float d0 = xi0 - h0, d1 = xi1 - h1, d2 = xi2 - h2;
      const float w = __expf(-(d0 * d0 + d1 * d1 + d2 * d2));
      a0 += w * h0; a1 += w * h1; a2 += w * h2; den += w;
    }
  }
  const float inv = 1.0f / den;  // den >= 1 (self term)
  hagg[((size_t)b * NPTS + i) * 3 + 0] = a0 * inv;
  hagg[((size_t)b * NPTS + i) * 3 + 1] = a1 * inv;
  hagg[((size_t)b * NPTS + i) * 3 + 2] = a2 * inv;
}

// ---------------------------------------------------------------------------
// aggregation for DIN in {64,128}: block tile = 64 rows x DIN cols,
// j staged in 64-wide tiles. Thread micro-tile: 4 rows x (DIN/16) cols.
// w tile (64x64) computed into LDS each j-tile (layout sw[j][i] so the
// GEMM phase reads 4 w's per row-group as one float4).
// ---------------------------------------------------------------------------
template <int DIN>
__global__ __launch_bounds__(256) void agg_kernel(const float* __restrict__ xc,
    const float* __restrict__ h, float* __restrict__ hagg) {
  constexpr int ND = DIN / 16;
  const int b = blockIdx.y;
  const int i0 = blockIdx.x * 64;
  const int tid = threadIdx.x;
  const int tx = tid >> 4;   // 0..15 : row-group (4 rows each)
  const int ty = tid & 15;   // 0..15 : col-group (ND cols each)
  const float* xb = xc + (size_t)b * NPTS * 3;

  __shared__ float sh[64 * DIN];   // h tile
  __shared__ float sw[64 * 64];    // w tile, [j][i]

  float xi[4][3];
#pragma unroll
  for (int mi = 0; mi < 4; mi++) {
    const int il = i0 + tx * 4 + mi;
    xi[mi][0] = xb[il * 3 + 0];
    xi[mi][1] = xb[il * 3 + 1];
    xi[mi][2] = xb[il * 3 + 2];
  }

  float acc[4][ND];
  float den[4] = {0.f, 0.f, 0.f, 0.f};
#pragma unroll
  for (int mi = 0; mi < 4; mi++)
#pragma unroll
    for (int e = 0; e < ND; e++) acc[mi][e] = 0.f;

  const float* hb = h + (size_t)b * NPTS * DIN;

  for (int j0 = 0; j0 < NPTS; j0 += 64) {
    __syncthreads();  // previous GEMM phase done before overwriting sh/sw
    // stage h tile (contiguous 64*DIN floats), float4 coalesced
    {
      const float4* src4 = (const float4*)(hb + (size_t)j0 * DIN);
      float4* dst4 = (float4*)sh;
#pragma unroll
      for (int t = 0; t < (64 * DIN / 4) / 256; t++)
        dst4[tid + t * 256] = src4[tid + t * 256];
    }
    // compute w 4x4 block: rows jl = ty*4+q, cols il = tx*4+mi
#pragma unroll
    for (int q = 0; q < 4; q++) {
      const int jl = ty * 4 + q;
      const float xj0 = xb[(j0 + jl) * 3 + 0];
      const float xj1 = xb[(j0 + jl) * 3 + 1];
      const float xj2 = xb[(j0 + jl) * 3 + 2];
      float4 w4;
      float* wp = (float*)&w4;
#pragma unroll
      for (int mi = 0; mi < 4; mi++) {
        const float d0 = xi[mi][0] - xj0;
        const float d1 = xi[mi][1] - xj1;
        const float d2 = xi[mi][2] - xj2;
        wp[mi] = __expf(-(d0 * d0 + d1 * d1 + d2 * d2));
      }
      *(float4*)&sw[jl * 64 + tx * 4] = w4;
    }
    __syncthreads();
    // GEMM phase
#pragma unroll 8
    for (int jj = 0; jj < 64; jj++) {
      const float4 w4 = *(const float4*)&sw[jj * 64 + tx * 4];
      const float* wp = (const float*)&w4;
      float hv[ND];
#pragma unroll
      for (int e = 0; e < ND; e += 4)
        *(float4*)&hv[e] = *(const float4*)&sh[jj * DIN + ty * ND + e];
#pragma unroll
      for (int mi = 0; mi < 4; mi++) {
        den[mi] += wp[mi];
#pragma unroll
        for (int e = 0; e < ND; e++) acc[mi][e] += wp[mi] * hv[e];
      }
    }
  }

#pragma unroll
  for (int mi = 0; mi < 4; mi++) {
    const int il = tx * 4 + mi;
    const float inv = 1.0f / den[mi];
    float* op = hagg + ((size_t)b * NPTS + i0 + il) * DIN + ty * ND;
#pragma unroll
    for (int e = 0; e < ND; e++) op[e] = acc[mi][e] * inv;
  }
}

// ---------------------------------------------------------------------------
// dense + layernorm + swish. 16 rows per block, one wave per 4 rows.
// Each lane owns DOUT/64 output columns.
// ---------------------------------------------------------------------------
template <int DIN, int DOUT>
__global__ __launch_bounds__(256) void mlp_kernel(const float* __restrict__ hagg,
    const float* __restrict__ W, const float* __restrict__ bias,
    const float* __restrict__ g, const float* __restrict__ be,
    float* __restrict__ hout) {
  constexpr int NO = DOUT / 64;
  const int tid = threadIdx.x;
  const int wv = tid >> 6;
  const int lane = tid & 63;
  const int r0 = blockIdx.x * 16;
  __shared__ float srow[16 * DIN];
  for (int idx = tid; idx < 16 * DIN; idx += 256)
    srow[idx] = hagg[(size_t)r0 * DIN + idx];
  __syncthreads();

  float o[4][NO];
#pragma unroll
  for (int e = 0; e < NO; e++) {
    const float bv = bias[lane + 64 * e];
#pragma unroll
    for (int r = 0; r < 4; r++) o[r][e] = bv;
  }
  for (int k = 0; k < DIN; k++) {
    float wreg[NO];
#pragma unroll
    for (int e = 0; e < NO; e++) wreg[e] = W[(size_t)k * DOUT + lane + 64 * e];
#pragma unroll
    for (int r = 0; r < 4; r++) {
      const float hr = srow[(wv * 4 + r) * DIN + k];
#pragma unroll
      for (int e = 0; e < NO; e++) o[r][e] += hr * wreg[e];
    }
  }
#pragma unroll
  for (int r = 0; r < 4; r++) {
    float m1 = 0.f, m2 = 0.f;
#pragma unroll
    for (int e = 0; e < NO; e++) { m1 += o[r][e]; m2 += o[r][e] * o[r][e]; }
#pragma unroll
    for (int off = 32; off > 0; off >>= 1) {
      m1 += __shfl_xor(m1, off, 64);
      m2 += __shfl_xor(m2, off, 64);
    }
    const float mu = m1 / DOUT;
    const float var = m2 / DOUT - mu * mu;
    const float rstd = rsqrtf(var + 1e-6f);
#pragma unroll
    for (int e = 0; e < NO; e++) {
      const int dco = lane + 64 * e;
      const float v = (o[r][e] - mu) * rstd * g[dco] + be[dco];
      const float sig = 1.0f / (1.0f + __expf(-v));
      hout[((size_t)r0 + wv * 4 + r) * DOUT + dco] = v * sig;
    }
  }
}

// ---------------------------------------------------------------------------
// masked mean pool (over N) + Dense(256 -> 128). One block per batch.
// ---------------------------------------------------------------------------
__global__ __launch_bounds__(256) void pool_kernel(const float* __restrict__ h3,
    const float* __restrict__ mask, const float* __restrict__ Wz,
    const float* __restrict__ bz, float* __restrict__ out) {
  const int b = blockIdx.x;
  const int tid = threadIdx.x;
  const float* hb = h3 + (size_t)b * NPTS * 256;
  const float* mb = mask + (size_t)b * NPTS;
  float s0 = 0.f, s1 = 0.f, s2 = 0.f, s3 = 0.f;
  for (int n = 0; n < NPTS; n += 4) {
    s0 += hb[(size_t)(n + 0) * 256 + tid] * mb[n + 0];
    s1 += hb[(size_t)(n + 1) * 256 + tid] * mb[n + 1];
    s2 += hb[(size_t)(n + 2) * 256 + tid] * mb[n + 2];
    s3 += hb[(size_t)(n + 3) * 256 + tid] * mb[n + 3];
  }
  const float s = (s0 + s1) + (s2 + s3);
  float c = 0.f;
  for (int n = tid; n < NPTS; n += 256) c += mb[n];
  __shared__ float red[256];
  red[tid] = c;
  __syncthreads();
  for (int off = 128; off > 0; off >>= 1) {
    if (tid < off) red[tid] += red[tid + off];
    __syncthreads();
  }
  const float cnt = fmaxf(red[0], 1.0f);
  __shared__ float gf[256];
  gf[tid] = s / cnt;
  __syncthreads();
  if (tid < LATENT) {
    float z = bz[tid];
#pragma unroll 4
    for (int d = 0; d < 256; d++) z += gf[d] * Wz[(size_t)d * LATENT + tid];
    out[(size_t)b * LATENT + tid] = z;
  }
}

// ---------------------------------------------------------------------------
extern "C" void kernel_launch(void* const* d_in, const int* in_sizes, int n_in,
                              void* d_out, int out_size, void* d_ws, size_t ws_size,
                              hipStream_t stream) {
  const float* x    = (const float*)d_in[0];
  const float* mask = (const float*)d_in[1];
  const float* W0   = (const float*)d_in[2];
  const float* b0   = (const float*)d_in[3];
  const float* g0   = (const float*)d_in[4];
  const float* be0  = (const float*)d_in[5];
  const float* W1   = (const float*)d_in[6];
  const float* b1   = (const float*)d_in[7];
  const float* g1   = (const float*)d_in[8];
  const float* be1  = (const float*)d_in[9];
  const float* W2   = (const float*)d_in[10];
  const float* b2   = (const float*)d_in[11];
  const float* g2   = (const float*)d_in[12];
  const float* be2  = (const float*)d_in[13];
  const float* Wz   = (const float*)d_in[14];
  const float* bz   = (const float*)d_in[15];
  float* out = (float*)d_out;

  // workspace layout (floats)
  float* ws   = (float*)d_ws;
  float* xc   = ws;                  // 8*2048*3   =   49152
  float* hagg = xc + 49152;          // max 8*2048*128 = 2097152
  float* h1   = hagg + 2097152;      // 8*2048*64  = 1048576
  float* h2   = h1 + 1048576;        // 8*2048*128 = 2097152
  float* h3   = h2 + 2097152;        // 8*2048*256 = 4194304
  // total ~36.2 MB

  centroid_kernel<<<dim3(BATCH), dim3(256), 0, stream>>>(x, mask, xc);

  // layer 0: h = xc (DIN=3)
  agg3_kernel<<<dim3(NPTS / 256, BATCH), dim3(256), 0, stream>>>(xc, hagg);
  mlp_kernel<3, 64><<<dim3(BATCH * NPTS / 16), dim3(256), 0, stream>>>(
      hagg, W0, b0, g0, be0, h1);

  // layer 1 (DIN=64 -> 128)
  agg_kernel<64><<<dim3(NPTS / 64, BATCH), dim3(256), 0, stream>>>(xc, h1, hagg);
  mlp_kernel<64, 128><<<dim3(BATCH * NPTS / 16), dim3(256), 0, stream>>>(
      hagg, W1, b1, g1, be1, h2);

  // layer 2 (DIN=128 -> 256)
  agg_kernel<128><<<dim3(NPTS / 64, BATCH), dim3(256), 0, stream>>>(xc, h2, hagg);
  mlp_kernel<128, 256><<<dim3(BATCH * NPTS / 16), dim3(256), 0, stream>>>(
      hagg, W2, b2, g2, be2, h3);

  // readout
  pool_kernel<<<dim3(BATCH), dim3(256), 0, stream>>>(h3, mask, Wz, bz, out);
}

// Round 2
// 292.476 us; speedup vs baseline: 2.2338x; 2.2338x over previous
//
#include <hip/hip_runtime.h>
#include <hip/hip_bf16.h>

#define BATCH 8
#define NPTS 2048
#define LATENT 128
#define KSPLIT 2

typedef __attribute__((ext_vector_type(8))) short short8;
typedef __attribute__((ext_vector_type(4))) float f32x4;

__device__ __forceinline__ ushort f2bf(float f) {
  unsigned int b = __float_as_uint(f);
  b += 0x7FFF + ((b >> 16) & 1);
  return (ushort)(b >> 16);
}
__device__ __forceinline__ float bf2f(ushort u) {
  return __uint_as_float(((unsigned int)u) << 16);
}

// ---------------------------------------------------------------------------
// prep: centroid + write pnt[b][n] = (sqrt2*xc, -|xc|^2) so that
// -dist_ij = pi.w + pj.w + dot(pi.xyz, pj.xyz). One block per batch.
// ---------------------------------------------------------------------------
__global__ __launch_bounds__(256) void prep_kernel(const float* __restrict__ x,
    const float* __restrict__ mask, float4* __restrict__ pnt) {
  const int b = blockIdx.x;
  const int tid = threadIdx.x;
  const float* xb = x + (size_t)b * NPTS * 3;
  const float* mb = mask + (size_t)b * NPTS;
  float s0 = 0.f, s1 = 0.f, s2 = 0.f, c = 0.f;
  for (int n = tid; n < NPTS; n += 256) {
    float m = mb[n];
    s0 += xb[n * 3 + 0] * m;
    s1 += xb[n * 3 + 1] * m;
    s2 += xb[n * 3 + 2] * m;
    c += m;
  }
  __shared__ float red[4][256];
  red[0][tid] = s0; red[1][tid] = s1; red[2][tid] = s2; red[3][tid] = c;
  __syncthreads();
  for (int off = 128; off > 0; off >>= 1) {
    if (tid < off) {
      red[0][tid] += red[0][tid + off];
      red[1][tid] += red[1][tid + off];
      red[2][tid] += red[2][tid + off];
      red[3][tid] += red[3][tid + off];
    }
    __syncthreads();
  }
  const float cnt = fmaxf(red[3][0], 1.0f);
  const float c0 = red[0][0] / cnt, c1 = red[1][0] / cnt, c2 = red[2][0] / cnt;
  const float SQ2 = 1.41421356237f;
  float4* pb = pnt + (size_t)b * NPTS;
  for (int n = tid; n < NPTS; n += 256) {
    const float a0 = xb[n * 3 + 0] - c0;
    const float a1 = xb[n * 3 + 1] - c1;
    const float a2 = xb[n * 3 + 2] - c2;
    pb[n] = make_float4(a0 * SQ2, a1 * SQ2, a2 * SQ2,
                        -(a0 * a0 + a1 * a1 + a2 * a2));
  }
}

// ---------------------------------------------------------------------------
// layer-0 aggregation (h == xc, D=3): 64 rows/block, 4-way j-split.
// Accumulates in u-space (u = sqrt2*xc) then rescales by 1/sqrt2.
// ---------------------------------------------------------------------------
__global__ __launch_bounds__(256) void agg3_kernel(const float4* __restrict__ pnt,
    float* __restrict__ hagg0) {
  const int b = blockIdx.y;
  const int i0 = blockIdx.x * 64;
  const int tid = threadIdx.x;
  const int il = tid & 63, part = tid >> 6;
  const float4* pb = pnt + (size_t)b * NPTS;
  const float4 pi = pb[i0 + il];
  float a0 = 0.f, a1 = 0.f, a2 = 0.f, dn = 0.f;
#pragma unroll 8
  for (int j = part * 512; j < part * 512 + 512; j++) {
    const float4 pj = pb[j];
    float arg = pi.w + pj.w;
    arg = fmaf(pi.x, pj.x, arg);
    arg = fmaf(pi.y, pj.y, arg);
    arg = fmaf(pi.z, pj.z, arg);
    const float w = __expf(arg);
    a0 = fmaf(w, pj.x, a0);
    a1 = fmaf(w, pj.y, a1);
    a2 = fmaf(w, pj.z, a2);
    dn += w;
  }
  __shared__ float4 sred[64][4];
  sred[il][part] = make_float4(a0, a1, a2, dn);
  __syncthreads();
  if (tid < 64) {
    const float4 r0 = sred[tid][0], r1 = sred[tid][1];
    const float r2x = sred[tid][2].x, r2y = sred[tid][2].y, r2z = sred[tid][2].z, r2w = sred[tid][2].w;
    const float4 r3 = sred[tid][3];
    const float A0 = r0.x + r1.x + r2x + r3.x;
    const float A1 = r0.y + r1.y + r2y + r3.y;
    const float A2 = r0.z + r1.z + r2z + r3.z;
    const float DN = r0.w + r1.w + r2w + r3.w;
    const float inv = 1.0f / (DN * 1.41421356237f);  // undo sqrt2 scaling
    float* op = hagg0 + ((size_t)b * NPTS + i0 + tid) * 3;
    op[0] = A0 * inv; op[1] = A1 * inv; op[2] = A2 * inv;
  }
}

// ---------------------------------------------------------------------------
// MFMA aggregation, DIN in {64,128}.
//   num[z][b][i][d] = sum_{j in z-chunk} w_ij * h[j][d]   (fp32 from MFMA)
//   den[z][b][i]    = sum_{j in z-chunk} w_ij             (fp32, VALU exact)
// A-fragments (w) are generated in registers per lane in exactly the MFMA
// A-layout A[m=lane&15][k=quad*8+jj] -> zero LDS traffic for w.
// B-fragments read from LDS tile of hT (pitch 72 -> 16B-aligned, bank-rotated).
// pnt tile is swizzled so the 4 quads hit 4 distinct bank groups.
// ---------------------------------------------------------------------------
template <int DIN>
__global__ __launch_bounds__(256, 2) void agg_mfma(
    const float4* __restrict__ pnt, const ushort* __restrict__ hT,
    float* __restrict__ num, float* __restrict__ den) {
  constexpr int NT = DIN / 16;
  constexpr int JCHUNK = NPTS / KSPLIT;
  constexpr int TILES = JCHUNK / 64;
  const int b = blockIdx.y, z = blockIdx.z;
  const int i0 = blockIdx.x * 64;
  const int tid = threadIdx.x;
  const int wv = tid >> 6, lane = tid & 63;
  const int m = lane & 15, q = lane >> 4;
  const float4* pb = pnt + (size_t)b * NPTS;
  const ushort* hb = hT + (size_t)b * DIN * NPTS;

  __shared__ ushort sht[2][DIN][72];   // [buf][d][j], pitch 72 (144B rows)
  __shared__ float4 spnt[2][64];       // [buf][swizzled j]

  const float4 pi = pb[i0 + wv * 16 + m];   // my A-row's point

  f32x4 acc[NT];
#pragma unroll
  for (int nt = 0; nt < NT; nt++)
#pragma unroll
    for (int e = 0; e < 4; e++) acc[nt][e] = 0.f;
  float dacc = 0.f;

  const int sc = tid & 7;            // 16B chunk within 64-j row
  const int sd = (tid >> 3) & 31;    // d-row
  const int jstart = z * JCHUNK;

  auto stage = [&](int jb, int bf) {
#pragma unroll
    for (int dd = 0; dd < DIN; dd += 32) {
      const uint4 v = *(const uint4*)(hb + (size_t)(dd + sd) * NPTS + jb + sc * 8);
      *(uint4*)&sht[bf][dd + sd][sc * 8] = v;
    }
    if (tid < 64) spnt[bf][((tid & 7) << 3) | (tid >> 3)] = pb[jb + tid];
  };

  stage(jstart, 0);
  __syncthreads();
  for (int t = 0; t < TILES; t++) {
    const int bf = t & 1;
    if (t + 1 < TILES) stage(jstart + (t + 1) * 64, bf ^ 1);
#pragma unroll
    for (int s = 0; s < 2; s++) {
      short8 af;
#pragma unroll
      for (int jj = 0; jj < 8; jj++) {
        const float4 pj = spnt[bf][(jj << 3) | (s * 4 + q)];
        float arg = pi.w + pj.w;
        arg = fmaf(pi.x, pj.x, arg);
        arg = fmaf(pi.y, pj.y, arg);
        arg = fmaf(pi.z, pj.z, arg);
        const float w = __expf(arg);   // exp(-dist_ij)
        dacc += w;
        af[jj] = (short)f2bf(w);
      }
#pragma unroll
      for (int nt = 0; nt < NT; nt++) {
        const short8 bfr = *(const short8*)&sht[bf][nt * 16 + m][s * 32 + q * 8];
        acc[nt] = __builtin_amdgcn_mfma_f32_16x16x32_bf16(af, bfr, acc[nt], 0, 0, 0);
      }
    }
    __syncthreads();
  }

  // den: lane holds partial for row (i0+16*wv+m); quads m,m+16,m+32,m+48 share it
  dacc += __shfl_xor(dacc, 16, 64);
  dacc += __shfl_xor(dacc, 32, 64);
  if (q == 0)
    den[(size_t)z * (BATCH * NPTS) + (size_t)b * NPTS + i0 + wv * 16 + m] = dacc;

  // C/D layout: col = lane&15 (d within tile), row = quad*4 + reg
  float* nb = num + (size_t)z * (size_t)(BATCH * NPTS) * DIN +
              ((size_t)b * NPTS + i0 + wv * 16) * DIN;
#pragma unroll
  for (int nt = 0; nt < NT; nt++)
#pragma unroll
    for (int r = 0; r < 4; r++)
      nb[(size_t)(q * 4 + r) * DIN + nt * 16 + m] = acc[nt][r];
}

// ---------------------------------------------------------------------------
// dense + layernorm + swish. 16 rows/block, one wave per 4 rows.
// SPLIT: input = (in0+in1)/(den0+den1) (combines agg split-K partials).
// TOUT:  write transposed bf16 hT[b][d][n] (for the next agg's B-operand);
// else:  write bf16 h[n][d] (for pool).
// ---------------------------------------------------------------------------
template <int DIN, int DOUT, bool SPLIT, bool TOUT>
__global__ __launch_bounds__(256) void mlp_kernel(
    const float* __restrict__ in0, const float* __restrict__ in1,
    const float* __restrict__ den0, const float* __restrict__ den1,
    const float* __restrict__ W, const float* __restrict__ bias,
    const float* __restrict__ g, const float* __restrict__ be,
    ushort* __restrict__ hout) {
  constexpr int NO = DOUT / 64;
  const int tid = threadIdx.x;
  const int wv = tid >> 6, lane = tid & 63;
  const int r0 = blockIdx.x * 16;
  __shared__ float srow[16 * DIN];
  __shared__ float sinv[16];
  if (SPLIT) {
    if (tid < 16) sinv[tid] = 1.0f / (den0[r0 + tid] + den1[r0 + tid]);
    __syncthreads();
    for (int idx = tid; idx < 16 * DIN; idx += 256) {
      const int r = idx / DIN;
      srow[idx] = (in0[(size_t)r0 * DIN + idx] + in1[(size_t)r0 * DIN + idx]) * sinv[r];
    }
  } else {
    for (int idx = tid; idx < 16 * DIN; idx += 256)
      srow[idx] = in0[(size_t)r0 * DIN + idx];
  }
  __syncthreads();

  float o[4][NO];
#pragma unroll
  for (int e = 0; e < NO; e++) {
    const float bv = bias[lane + 64 * e];
#pragma unroll
    for (int r = 0; r < 4; r++) o[r][e] = bv;
  }
  for (int k = 0; k < DIN; k++) {
    float wreg[NO];
#pragma unroll
    for (int e = 0; e < NO; e++) wreg[e] = W[(size_t)k * DOUT + lane + 64 * e];
#pragma unroll
    for (int r = 0; r < 4; r++) {
      const float hr = srow[(wv * 4 + r) * DIN + k];
#pragma unroll
      for (int e = 0; e < NO; e++) o[r][e] = fmaf(hr, wreg[e], o[r][e]);
    }
  }

  __shared__ ushort lt[TOUT ? DOUT : 1][16];
#pragma unroll
  for (int r = 0; r < 4; r++) {
    float m1 = 0.f, m2 = 0.f;
#pragma unroll
    for (int e = 0; e < NO; e++) { m1 += o[r][e]; m2 += o[r][e] * o[r][e]; }
#pragma unroll
    for (int off = 32; off > 0; off >>= 1) {
      m1 += __shfl_xor(m1, off, 64);
      m2 += __shfl_xor(m2, off, 64);
    }
    const float mu = m1 / DOUT;
    const float var = m2 / DOUT - mu * mu;
    const float rstd = rsqrtf(var + 1e-6f);
#pragma unroll
    for (int e = 0; e < NO; e++) {
      const int dco = lane + 64 * e;
      const float v = (o[r][e] - mu) * rstd * g[dco] + be[dco];
      const float act = v / (1.0f + __expf(-v));
      if (TOUT) lt[dco][wv * 4 + r] = f2bf(act);
      else hout[(size_t)(r0 + wv * 4 + r) * DOUT + dco] = f2bf(act);
    }
  }
  if (TOUT) {
    __syncthreads();
    if (tid < DOUT) {
      const uint4 v0 = *(const uint4*)&lt[tid][0];
      const uint4 v1 = *(const uint4*)&lt[tid][8];
      const int bb = r0 / NPTS;
      const int nn = r0 % NPTS;
      ushort* dst = hout + ((size_t)bb * DOUT + tid) * NPTS + nn;
      *(uint4*)dst = v0;
      *(uint4*)(dst + 8) = v1;
    }
  }
}

// ---------------------------------------------------------------------------
// masked mean pool over N (h3 is bf16 [n][256]) + Dense(256 -> 128).
// ---------------------------------------------------------------------------
__global__ __launch_bounds__(256) void pool_kernel(const ushort* __restrict__ h3,
    const float* __restrict__ mask, const float* __restrict__ Wz,
    const float* __restrict__ bz, float* __restrict__ out) {
  const int b = blockIdx.x;
  const int tid = threadIdx.x;
  const ushort* hb = h3 + (size_t)b * NPTS * 256;
  const float* mb = mask + (size_t)b * NPTS;
  float s0 = 0.f, s1 = 0.f, s2 = 0.f, s3 = 0.f;
  for (int n = 0; n < NPTS; n += 4) {
    s0 += bf2f(hb[(size_t)(n + 0) * 256 + tid]) * mb[n + 0];
    s1 += bf2f(hb[(size_t)(n + 1) * 256 + tid]) * mb[n + 1];
    s2 += bf2f(hb[(size_t)(n + 2) * 256 + tid]) * mb[n + 2];
    s3 += bf2f(hb[(size_t)(n + 3) * 256 + tid]) * mb[n + 3];
  }
  const float s = (s0 + s1) + (s2 + s3);
  float c = 0.f;
  for (int n = tid; n < NPTS; n += 256) c += mb[n];
  __shared__ float red[256];
  red[tid] = c;
  __syncthreads();
  for (int off = 128; off > 0; off >>= 1) {
    if (tid < off) red[tid] += red[tid + off];
    __syncthreads();
  }
  const float cnt = fmaxf(red[0], 1.0f);
  __shared__ float gf[256];
  gf[tid] = s / cnt;
  __syncthreads();
  if (tid < LATENT) {
    float z = bz[tid];
#pragma unroll 4
    for (int d = 0; d < 256; d++) z += gf[d] * Wz[(size_t)d * LATENT + tid];
    out[(size_t)b * LATENT + tid] = z;
  }
}

// ---------------------------------------------------------------------------
extern "C" void kernel_launch(void* const* d_in, const int* in_sizes, int n_in,
                              void* d_out, int out_size, void* d_ws, size_t ws_size,
                              hipStream_t stream) {
  const float* x    = (const float*)d_in[0];
  const float* mask = (const float*)d_in[1];
  const float* W0   = (const float*)d_in[2];
  const float* b0   = (const float*)d_in[3];
  const float* g0   = (const float*)d_in[4];
  const float* be0  = (const float*)d_in[5];
  const float* W1   = (const float*)d_in[6];
  const float* b1   = (const float*)d_in[7];
  const float* g1   = (const float*)d_in[8];
  const float* be1  = (const float*)d_in[9];
  const float* W2   = (const float*)d_in[10];
  const float* b2   = (const float*)d_in[11];
  const float* g2   = (const float*)d_in[12];
  const float* be2  = (const float*)d_in[13];
  const float* Wz   = (const float*)d_in[14];
  const float* bz   = (const float*)d_in[15];
  float* out = (float*)d_out;

  // workspace layout (bytes, 16B-aligned regions)
  char* ws = (char*)d_ws;
  float4* pnt   = (float4*)(ws);                       // 8*2048*16   =  262144 B
  float*  hagg0 = (float*)(ws + 262144);               // 8*2048*3*4  =  196608 B
  float*  num   = (float*)(ws + 458752);               // 2*8*2048*128*4 = 16777216 B
  float*  den   = (float*)(ws + 17235968);             // 2*8*2048*4  =  131072 B
  ushort* h1T   = (ushort*)(ws + 17367040);            // 8*64*2048*2 = 2097152 B
  ushort* h2T   = (ushort*)(ws + 19464192);            // 8*128*2048*2= 4194304 B
  ushort* h3    = (ushort*)(ws + 23658496);            // 8*2048*256*2= 8388608 B
  // total ~32.0 MB

  prep_kernel<<<dim3(BATCH), dim3(256), 0, stream>>>(x, mask, pnt);

  // layer 0: h = xc (D=3), VALU fp32
  agg3_kernel<<<dim3(NPTS / 64, BATCH), dim3(256), 0, stream>>>(pnt, hagg0);
  mlp_kernel<3, 64, false, true><<<dim3(BATCH * NPTS / 16), dim3(256), 0, stream>>>(
      hagg0, nullptr, nullptr, nullptr, W0, b0, g0, be0, h1T);

  // layer 1 (64 -> 128), MFMA
  agg_mfma<64><<<dim3(NPTS / 64, BATCH, KSPLIT), dim3(256), 0, stream>>>(
      pnt, h1T, num, den);
  mlp_kernel<64, 128, true, true><<<dim3(BATCH * NPTS / 16), dim3(256), 0, stream>>>(
      num, num + (size_t)BATCH * NPTS * 64, den, den + (size_t)BATCH * NPTS,
      W1, b1, g1, be1, h2T);

  // layer 2 (128 -> 256), MFMA
  agg_mfma<128><<<dim3(NPTS / 64, BATCH, KSPLIT), dim3(256), 0, stream>>>(
      pnt, h2T, num, den);
  mlp_kernel<128, 256, true, false><<<dim3(BATCH * NPTS / 16), dim3(256), 0, stream>>>(
      num, num + (size_t)BATCH * NPTS * 128, den, den + (size_t)BATCH * NPTS,
      W2, b2, g2, be2, h3);

  // readout
  pool_kernel<<<dim3(BATCH), dim3(256), 0, stream>>>(h3, mask, Wz, bz, out);
}

// Round 3
// 241.456 us; speedup vs baseline: 2.7058x; 1.2113x over previous
//
#include <hip/hip_runtime.h>
#include <hip/hip_bf16.h>

#define BATCH 8
#define NPTS 2048
#define LATENT 128
#define KSPLIT 2

typedef __attribute__((ext_vector_type(8))) short short8;
typedef __attribute__((ext_vector_type(4))) float f32x4;

__device__ __forceinline__ ushort f2bf(float f) {
  unsigned int b = __float_as_uint(f);
  b += 0x7FFF + ((b >> 16) & 1);
  return (ushort)(b >> 16);
}

// ---------------------------------------------------------------------------
// prep: centroid + write pnt[b][n] = (sqrt2*xc, -|xc|^2) so that
// -dist_ij = pi.w + pj.w + dot(pi.xyz, pj.xyz). One block per batch.
// ---------------------------------------------------------------------------
__global__ __launch_bounds__(256) void prep_kernel(const float* __restrict__ x,
    const float* __restrict__ mask, float4* __restrict__ pnt) {
  const int b = blockIdx.x;
  const int tid = threadIdx.x;
  const float* xb = x + (size_t)b * NPTS * 3;
  const float* mb = mask + (size_t)b * NPTS;
  float s0 = 0.f, s1 = 0.f, s2 = 0.f, c = 0.f;
  for (int n = tid; n < NPTS; n += 256) {
    float m = mb[n];
    s0 += xb[n * 3 + 0] * m;
    s1 += xb[n * 3 + 1] * m;
    s2 += xb[n * 3 + 2] * m;
    c += m;
  }
  __shared__ float red[4][256];
  red[0][tid] = s0; red[1][tid] = s1; red[2][tid] = s2; red[3][tid] = c;
  __syncthreads();
  for (int off = 128; off > 0; off >>= 1) {
    if (tid < off) {
      red[0][tid] += red[0][tid + off];
      red[1][tid] += red[1][tid + off];
      red[2][tid] += red[2][tid + off];
      red[3][tid] += red[3][tid + off];
    }
    __syncthreads();
  }
  const float cnt = fmaxf(red[3][0], 1.0f);
  const float c0 = red[0][0] / cnt, c1 = red[1][0] / cnt, c2 = red[2][0] / cnt;
  const float SQ2 = 1.41421356237f;
  float4* pb = pnt + (size_t)b * NPTS;
  for (int n = tid; n < NPTS; n += 256) {
    const float a0 = xb[n * 3 + 0] - c0;
    const float a1 = xb[n * 3 + 1] - c1;
    const float a2 = xb[n * 3 + 2] - c2;
    pb[n] = make_float4(a0 * SQ2, a1 * SQ2, a2 * SQ2,
                        -(a0 * a0 + a1 * a1 + a2 * a2));
  }
}

// ---------------------------------------------------------------------------
// layer-0 aggregation (h == xc, D=3): 64 rows/block, 4-way j-split.
// ---------------------------------------------------------------------------
__global__ __launch_bounds__(256) void agg3_kernel(const float4* __restrict__ pnt,
    float* __restrict__ hagg0) {
  const int b = blockIdx.y;
  const int i0 = blockIdx.x * 64;
  const int tid = threadIdx.x;
  const int il = tid & 63, part = tid >> 6;
  const float4* pb = pnt + (size_t)b * NPTS;
  const float4 pi = pb[i0 + il];
  float a0 = 0.f, a1 = 0.f, a2 = 0.f, dn = 0.f;
#pragma unroll 8
  for (int j = part * 512; j < part * 512 + 512; j++) {
    const float4 pj = pb[j];
    float arg = pi.w + pj.w;
    arg = fmaf(pi.x, pj.x, arg);
    arg = fmaf(pi.y, pj.y, arg);
    arg = fmaf(pi.z, pj.z, arg);
    const float w = __expf(arg);
    a0 = fmaf(w, pj.x, a0);
    a1 = fmaf(w, pj.y, a1);
    a2 = fmaf(w, pj.z, a2);
    dn += w;
  }
  __shared__ float4 sred[64][4];
  sred[il][part] = make_float4(a0, a1, a2, dn);
  __syncthreads();
  if (tid < 64) {
    const float4 r0 = sred[tid][0], r1 = sred[tid][1];
    const float r2x = sred[tid][2].x, r2y = sred[tid][2].y, r2z = sred[tid][2].z, r2w = sred[tid][2].w;
    const float4 r3 = sred[tid][3];
    const float A0 = r0.x + r1.x + r2x + r3.x;
    const float A1 = r0.y + r1.y + r2y + r3.y;
    const float A2 = r0.z + r1.z + r2z + r3.z;
    const float DN = r0.w + r1.w + r2w + r3.w;
    const float inv = 1.0f / (DN * 1.41421356237f);  // undo sqrt2 scaling
    float* op = hagg0 + ((size_t)b * NPTS + i0 + tid) * 3;
    op[0] = A0 * inv; op[1] = A1 * inv; op[2] = A2 * inv;
  }
}

// ---------------------------------------------------------------------------
// MFMA aggregation, DIN in {64,128}. A (= w weights) generated in registers
// in MFMA A-layout; B (= hT) staged in padded, double-buffered LDS.
// ---------------------------------------------------------------------------
template <int DIN>
__global__ __launch_bounds__(256, 2) void agg_mfma(
    const float4* __restrict__ pnt, const ushort* __restrict__ hT,
    float* __restrict__ num, float* __restrict__ den) {
  constexpr int NT = DIN / 16;
  constexpr int JCHUNK = NPTS / KSPLIT;
  constexpr int TILES = JCHUNK / 64;
  const int b = blockIdx.y, z = blockIdx.z;
  const int i0 = blockIdx.x * 64;
  const int tid = threadIdx.x;
  const int wv = tid >> 6, lane = tid & 63;
  const int m = lane & 15, q = lane >> 4;
  const float4* pb = pnt + (size_t)b * NPTS;
  const ushort* hb = hT + (size_t)b * DIN * NPTS;

  __shared__ ushort sht[2][DIN][72];   // [buf][d][j], pitch 72 (144B rows)
  __shared__ float4 spnt[2][64];       // [buf][swizzled j]

  const float4 pi = pb[i0 + wv * 16 + m];   // my A-row's point

  f32x4 acc[NT];
#pragma unroll
  for (int nt = 0; nt < NT; nt++)
#pragma unroll
    for (int e = 0; e < 4; e++) acc[nt][e] = 0.f;
  float dacc = 0.f;

  const int sc = tid & 7;            // 16B chunk within 64-j row
  const int sd = (tid >> 3) & 31;    // d-row
  const int jstart = z * JCHUNK;

  auto stage = [&](int jb, int bf) {
#pragma unroll
    for (int dd = 0; dd < DIN; dd += 32) {
      const uint4 v = *(const uint4*)(hb + (size_t)(dd + sd) * NPTS + jb + sc * 8);
      *(uint4*)&sht[bf][dd + sd][sc * 8] = v;
    }
    if (tid < 64) spnt[bf][((tid & 7) << 3) | (tid >> 3)] = pb[jb + tid];
  };

  stage(jstart, 0);
  __syncthreads();
  for (int t = 0; t < TILES; t++) {
    const int bf = t & 1;
    if (t + 1 < TILES) stage(jstart + (t + 1) * 64, bf ^ 1);
#pragma unroll
    for (int s = 0; s < 2; s++) {
      short8 af;
#pragma unroll
      for (int jj = 0; jj < 8; jj++) {
        const float4 pj = spnt[bf][(jj << 3) | (s * 4 + q)];
        float arg = pi.w + pj.w;
        arg = fmaf(pi.x, pj.x, arg);
        arg = fmaf(pi.y, pj.y, arg);
        arg = fmaf(pi.z, pj.z, arg);
        const float w = __expf(arg);   // exp(-dist_ij)
        dacc += w;
        af[jj] = (short)f2bf(w);
      }
#pragma unroll
      for (int nt = 0; nt < NT; nt++) {
        const short8 bfr = *(const short8*)&sht[bf][nt * 16 + m][s * 32 + q * 8];
        acc[nt] = __builtin_amdgcn_mfma_f32_16x16x32_bf16(af, bfr, acc[nt], 0, 0, 0);
      }
    }
    __syncthreads();
  }

  dacc += __shfl_xor(dacc, 16, 64);
  dacc += __shfl_xor(dacc, 32, 64);
  if (q == 0)
    den[(size_t)z * (BATCH * NPTS) + (size_t)b * NPTS + i0 + wv * 16 + m] = dacc;

  // C/D layout: col = lane&15 (d within tile), row = quad*4 + reg
  float* nb = num + (size_t)z * (size_t)(BATCH * NPTS) * DIN +
              ((size_t)b * NPTS + i0 + wv * 16) * DIN;
#pragma unroll
  for (int nt = 0; nt < NT; nt++)
#pragma unroll
    for (int r = 0; r < 4; r++)
      nb[(size_t)(q * 4 + r) * DIN + nt * 16 + m] = acc[nt][r];
}

// ---------------------------------------------------------------------------
// dense + layernorm + swish. 16 rows/block, one wave per 4 rows.
// SPLIT: input = (in0+in1)/(den0+den1)  (combines agg split-K partials)
// TOUT:  write transposed bf16 hT[b][d][n] (next agg's B-operand)
// POOL:  don't write h at all; reduce mask-weighted column sums across the
//        block's 16 rows and emit one fp32 partial[b][blk][DOUT] row.
// ---------------------------------------------------------------------------
template <int DIN, int DOUT, bool SPLIT, bool TOUT, bool POOL>
__global__ __launch_bounds__(256) void mlp_kernel(
    const float* __restrict__ in0, const float* __restrict__ in1,
    const float* __restrict__ den0, const float* __restrict__ den1,
    const float* __restrict__ W, const float* __restrict__ bias,
    const float* __restrict__ g, const float* __restrict__ be,
    ushort* __restrict__ hout, const float* __restrict__ mask,
    float* __restrict__ partial) {
  constexpr int NO = DOUT / 64;
  const int tid = threadIdx.x;
  const int wv = tid >> 6, lane = tid & 63;
  const int r0 = blockIdx.x * 16;
  __shared__ float srow[16 * DIN];
  __shared__ float sinv[16];
  if (SPLIT) {
    if (tid < 16) sinv[tid] = 1.0f / (den0[r0 + tid] + den1[r0 + tid]);
    __syncthreads();
    for (int idx = tid; idx < 16 * DIN; idx += 256) {
      const int r = idx / DIN;
      srow[idx] = (in0[(size_t)r0 * DIN + idx] + in1[(size_t)r0 * DIN + idx]) * sinv[r];
    }
  } else {
    for (int idx = tid; idx < 16 * DIN; idx += 256)
      srow[idx] = in0[(size_t)r0 * DIN + idx];
  }
  __syncthreads();

  float o[4][NO];
#pragma unroll
  for (int e = 0; e < NO; e++) {
    const float bv = bias[lane + 64 * e];
#pragma unroll
    for (int r = 0; r < 4; r++) o[r][e] = bv;
  }
  for (int k = 0; k < DIN; k++) {
    float wreg[NO];
#pragma unroll
    for (int e = 0; e < NO; e++) wreg[e] = W[(size_t)k * DOUT + lane + 64 * e];
#pragma unroll
    for (int r = 0; r < 4; r++) {
      const float hr = srow[(wv * 4 + r) * DIN + k];
#pragma unroll
      for (int e = 0; e < NO; e++) o[r][e] = fmaf(hr, wreg[e], o[r][e]);
    }
  }

  __shared__ ushort lt[TOUT ? DOUT : 1][16];
  __shared__ float sp[POOL ? 4 : 1][POOL ? DOUT : 1];
  float pacc[NO];
  if (POOL) {
#pragma unroll
    for (int e = 0; e < NO; e++) pacc[e] = 0.f;
  }
  const int bb = r0 / NPTS;
  const int nn = r0 % NPTS;

#pragma unroll
  for (int r = 0; r < 4; r++) {
    float m1 = 0.f, m2 = 0.f;
#pragma unroll
    for (int e = 0; e < NO; e++) { m1 += o[r][e]; m2 += o[r][e] * o[r][e]; }
#pragma unroll
    for (int off = 32; off > 0; off >>= 1) {
      m1 += __shfl_xor(m1, off, 64);
      m2 += __shfl_xor(m2, off, 64);
    }
    const float mu = m1 / DOUT;
    const float var = m2 / DOUT - mu * mu;
    const float rstd = rsqrtf(var + 1e-6f);
    float mval = 0.f;
    if (POOL) mval = mask[(size_t)bb * NPTS + nn + wv * 4 + r];
#pragma unroll
    for (int e = 0; e < NO; e++) {
      const int dco = lane + 64 * e;
      const float v = (o[r][e] - mu) * rstd * g[dco] + be[dco];
      const float act = v / (1.0f + __expf(-v));
      if (POOL) pacc[e] = fmaf(act, mval, pacc[e]);
      else if (TOUT) lt[dco][wv * 4 + r] = f2bf(act);
      else hout[(size_t)(r0 + wv * 4 + r) * DOUT + dco] = f2bf(act);
    }
  }
  if (TOUT) {
    __syncthreads();
    if (tid < DOUT) {
      const uint4 v0 = *(const uint4*)&lt[tid][0];
      const uint4 v1 = *(const uint4*)&lt[tid][8];
      ushort* dst = hout + ((size_t)bb * DOUT + tid) * NPTS + nn;
      *(uint4*)dst = v0;
      *(uint4*)(dst + 8) = v1;
    }
  }
  if (POOL) {
#pragma unroll
    for (int e = 0; e < NO; e++) sp[wv][lane + 64 * e] = pacc[e];
    __syncthreads();
    if (tid < DOUT) {
      const float s = (sp[0][tid] + sp[1][tid]) + (sp[2][tid] + sp[3][tid]);
      partial[((size_t)bb * (NPTS / 16) + (nn / 16)) * DOUT + tid] = s;
    }
  }
}

// ---------------------------------------------------------------------------
// readout: reduce 128 partial rows per batch, divide by count, Dense(256->128)
// ---------------------------------------------------------------------------
__global__ __launch_bounds__(256) void readout_kernel(
    const float* __restrict__ partial, const float* __restrict__ mask,
    const float* __restrict__ Wz, const float* __restrict__ bz,
    float* __restrict__ out) {
  const int b = blockIdx.x;
  const int tid = threadIdx.x;
  const float* pb = partial + (size_t)b * (NPTS / 16) * 256;
  float s0 = 0.f, s1 = 0.f, s2 = 0.f, s3 = 0.f;
#pragma unroll 4
  for (int p = 0; p < NPTS / 16; p += 4) {
    s0 += pb[(size_t)(p + 0) * 256 + tid];
    s1 += pb[(size_t)(p + 1) * 256 + tid];
    s2 += pb[(size_t)(p + 2) * 256 + tid];
    s3 += pb[(size_t)(p + 3) * 256 + tid];
  }
  const float s = (s0 + s1) + (s2 + s3);
  const float* mb = mask + (size_t)b * NPTS;
  float c = 0.f;
  for (int n = tid; n < NPTS; n += 256) c += mb[n];
  __shared__ float red[256];
  red[tid] = c;
  __syncthreads();
  for (int off = 128; off > 0; off >>= 1) {
    if (tid < off) red[tid] += red[tid + off];
    __syncthreads();
  }
  const float cnt = fmaxf(red[0], 1.0f);
  __shared__ float gf[256];
  gf[tid] = s / cnt;
  __syncthreads();
  if (tid < LATENT) {
    float z = bz[tid];
#pragma unroll 4
    for (int d = 0; d < 256; d++) z += gf[d] * Wz[(size_t)d * LATENT + tid];
    out[(size_t)b * LATENT + tid] = z;
  }
}

// ---------------------------------------------------------------------------
extern "C" void kernel_launch(void* const* d_in, const int* in_sizes, int n_in,
                              void* d_out, int out_size, void* d_ws, size_t ws_size,
                              hipStream_t stream) {
  const float* x    = (const float*)d_in[0];
  const float* mask = (const float*)d_in[1];
  const float* W0   = (const float*)d_in[2];
  const float* b0   = (const float*)d_in[3];
  const float* g0   = (const float*)d_in[4];
  const float* be0  = (const float*)d_in[5];
  const float* W1   = (const float*)d_in[6];
  const float* b1   = (const float*)d_in[7];
  const float* g1   = (const float*)d_in[8];
  const float* be1  = (const float*)d_in[9];
  const float* W2   = (const float*)d_in[10];
  const float* b2   = (const float*)d_in[11];
  const float* g2   = (const float*)d_in[12];
  const float* be2  = (const float*)d_in[13];
  const float* Wz   = (const float*)d_in[14];
  const float* bz   = (const float*)d_in[15];
  float* out = (float*)d_out;

  // workspace layout (bytes, 16B-aligned regions)
  char* ws = (char*)d_ws;
  float4* pnt     = (float4*)(ws);                     // 262144 B
  float*  hagg0   = (float*)(ws + 262144);             // 196608 B
  float*  num     = (float*)(ws + 458752);             // 16777216 B
  float*  den     = (float*)(ws + 17235968);           // 131072 B
  ushort* h1T     = (ushort*)(ws + 17367040);          // 2097152 B
  ushort* h2T     = (ushort*)(ws + 19464192);          // 4194304 B
  float*  partial = (float*)(ws + 23658496);           // 8*128*256*4 = 1048576 B
  // total ~24.7 MB

  prep_kernel<<<dim3(BATCH), dim3(256), 0, stream>>>(x, mask, pnt);

  // layer 0: h = xc (D=3), VALU fp32
  agg3_kernel<<<dim3(NPTS / 64, BATCH), dim3(256), 0, stream>>>(pnt, hagg0);
  mlp_kernel<3, 64, false, true, false><<<dim3(BATCH * NPTS / 16), dim3(256), 0, stream>>>(
      hagg0, nullptr, nullptr, nullptr, W0, b0, g0, be0, h1T, nullptr, nullptr);

  // layer 1 (64 -> 128), MFMA
  agg_mfma<64><<<dim3(NPTS / 64, BATCH, KSPLIT), dim3(256), 0, stream>>>(
      pnt, h1T, num, den);
  mlp_kernel<64, 128, true, true, false><<<dim3(BATCH * NPTS / 16), dim3(256), 0, stream>>>(
      num, num + (size_t)BATCH * NPTS * 64, den, den + (size_t)BATCH * NPTS,
      W1, b1, g1, be1, h2T, nullptr, nullptr);

  // layer 2 (128 -> 256), MFMA + fused masked-sum pooling
  agg_mfma<128><<<dim3(NPTS / 64, BATCH, KSPLIT), dim3(256), 0, stream>>>(
      pnt, h2T, num, den);
  mlp_kernel<128, 256, true, false, true><<<dim3(BATCH * NPTS / 16), dim3(256), 0, stream>>>(
      num, num + (size_t)BATCH * NPTS * 128, den, den + (size_t)BATCH * NPTS,
      W2, b2, g2, be2, nullptr, mask, partial);

  // readout
  readout_kernel<<<dim3(BATCH), dim3(256), 0, stream>>>(partial, mask, Wz, bz, out);
}

// Round 4
// 234.005 us; speedup vs baseline: 2.7919x; 1.0318x over previous
//
#include <hip/hip_runtime.h>
#include <hip/hip_bf16.h>

#define BATCH 8
#define NPTS 2048
#define LATENT 128

typedef __attribute__((ext_vector_type(8))) short short8;
typedef __attribute__((ext_vector_type(4))) float f32x4;

__device__ __forceinline__ ushort f2bf(float f) {
  unsigned int b = __float_as_uint(f);
  b += 0x7FFF + ((b >> 16) & 1);
  return (ushort)(b >> 16);
}

// ---------------------------------------------------------------------------
// prep: centroid + write pnt[b][n] = (sqrt2*xc, -|xc|^2) so that
// -dist_ij = pi.w + pj.w + dot(pi.xyz, pj.xyz). One block per batch.
// ---------------------------------------------------------------------------
__global__ __launch_bounds__(256) void prep_kernel(const float* __restrict__ x,
    const float* __restrict__ mask, float4* __restrict__ pnt) {
  const int b = blockIdx.x;
  const int tid = threadIdx.x;
  const float* xb = x + (size_t)b * NPTS * 3;
  const float* mb = mask + (size_t)b * NPTS;
  float s0 = 0.f, s1 = 0.f, s2 = 0.f, c = 0.f;
  for (int n = tid; n < NPTS; n += 256) {
    float m = mb[n];
    s0 += xb[n * 3 + 0] * m;
    s1 += xb[n * 3 + 1] * m;
    s2 += xb[n * 3 + 2] * m;
    c += m;
  }
  __shared__ float red[4][256];
  red[0][tid] = s0; red[1][tid] = s1; red[2][tid] = s2; red[3][tid] = c;
  __syncthreads();
  for (int off = 128; off > 0; off >>= 1) {
    if (tid < off) {
      red[0][tid] += red[0][tid + off];
      red[1][tid] += red[1][tid + off];
      red[2][tid] += red[2][tid + off];
      red[3][tid] += red[3][tid + off];
    }
    __syncthreads();
  }
  const float cnt = fmaxf(red[3][0], 1.0f);
  const float c0 = red[0][0] / cnt, c1 = red[1][0] / cnt, c2 = red[2][0] / cnt;
  const float SQ2 = 1.41421356237f;
  float4* pb = pnt + (size_t)b * NPTS;
  for (int n = tid; n < NPTS; n += 256) {
    const float a0 = xb[n * 3 + 0] - c0;
    const float a1 = xb[n * 3 + 1] - c1;
    const float a2 = xb[n * 3 + 2] - c2;
    pb[n] = make_float4(a0 * SQ2, a1 * SQ2, a2 * SQ2,
                        -(a0 * a0 + a1 * a1 + a2 * a2));
  }
}

// ---------------------------------------------------------------------------
// layer-0 aggregation (h == xc, D=3): 64 rows/block, 4-way j-split.
// ---------------------------------------------------------------------------
__global__ __launch_bounds__(256) void agg3_kernel(const float4* __restrict__ pnt,
    float* __restrict__ hagg0) {
  const int b = blockIdx.y;
  const int i0 = blockIdx.x * 64;
  const int tid = threadIdx.x;
  const int il = tid & 63, part = tid >> 6;
  const float4* pb = pnt + (size_t)b * NPTS;
  const float4 pi = pb[i0 + il];
  float a0 = 0.f, a1 = 0.f, a2 = 0.f, dn = 0.f;
#pragma unroll 8
  for (int j = part * 512; j < part * 512 + 512; j++) {
    const float4 pj = pb[j];
    float arg = pi.w + pj.w;
    arg = fmaf(pi.x, pj.x, arg);
    arg = fmaf(pi.y, pj.y, arg);
    arg = fmaf(pi.z, pj.z, arg);
    const float w = __expf(arg);
    a0 = fmaf(w, pj.x, a0);
    a1 = fmaf(w, pj.y, a1);
    a2 = fmaf(w, pj.z, a2);
    dn += w;
  }
  __shared__ float4 sred[64][4];
  sred[il][part] = make_float4(a0, a1, a2, dn);
  __syncthreads();
  if (tid < 64) {
    const float4 r0 = sred[tid][0], r1 = sred[tid][1];
    const float r2x = sred[tid][2].x, r2y = sred[tid][2].y, r2z = sred[tid][2].z, r2w = sred[tid][2].w;
    const float4 r3 = sred[tid][3];
    const float A0 = r0.x + r1.x + r2x + r3.x;
    const float A1 = r0.y + r1.y + r2y + r3.y;
    const float A2 = r0.z + r1.z + r2z + r3.z;
    const float DN = r0.w + r1.w + r2w + r3.w;
    const float inv = 1.0f / (DN * 1.41421356237f);  // undo sqrt2 scaling
    float* op = hagg0 + ((size_t)b * NPTS + i0 + tid) * 3;
    op[0] = A0 * inv; op[1] = A1 * inv; op[2] = A2 * inv;
  }
}

// ---------------------------------------------------------------------------
// layer-0 dense + LN + swish (DIN=3 -> DOUT=64), 16 rows/block,
// writes transposed bf16 h1T[b][d][n].
// ---------------------------------------------------------------------------
__global__ __launch_bounds__(256) void mlp0_kernel(
    const float* __restrict__ in0, const float* __restrict__ W,
    const float* __restrict__ bias, const float* __restrict__ g,
    const float* __restrict__ be, ushort* __restrict__ hout) {
  constexpr int DIN = 3, DOUT = 64;
  const int tid = threadIdx.x;
  const int wv = tid >> 6, lane = tid & 63;
  const int r0 = blockIdx.x * 16;
  __shared__ float srow[16 * DIN];
  if (tid < 16 * DIN) srow[tid] = in0[(size_t)r0 * DIN + tid];
  __syncthreads();

  float o[4];
  const float bv = bias[lane];
#pragma unroll
  for (int r = 0; r < 4; r++) o[r] = bv;
#pragma unroll
  for (int k = 0; k < DIN; k++) {
    const float wk = W[(size_t)k * DOUT + lane];
#pragma unroll
    for (int r = 0; r < 4; r++)
      o[r] = fmaf(srow[(wv * 4 + r) * DIN + k], wk, o[r]);
  }
  __shared__ ushort lt[16][DOUT];
#pragma unroll
  for (int r = 0; r < 4; r++) {
    float m1 = o[r], m2 = o[r] * o[r];
#pragma unroll
    for (int off = 32; off > 0; off >>= 1) {
      m1 += __shfl_xor(m1, off, 64);
      m2 += __shfl_xor(m2, off, 64);
    }
    const float mu = m1 / DOUT;
    const float var = m2 / DOUT - mu * mu;
    const float rstd = rsqrtf(var + 1e-6f);
    const float v = (o[r] - mu) * rstd * g[lane] + be[lane];
    const float act = v / (1.0f + __expf(-v));
    lt[wv * 4 + r][lane] = f2bf(act);
  }
  __syncthreads();
  if (tid < DOUT) {
    ushort tmp[16];
#pragma unroll
    for (int r = 0; r < 16; r++) tmp[r] = lt[r][tid];
    const int bb = r0 / NPTS;
    const int nn = r0 % NPTS;
    ushort* dst = hout + ((size_t)bb * DOUT + tid) * NPTS + nn;
    *(uint4*)dst = *(uint4*)&tmp[0];
    *(uint4*)(dst + 8) = *(uint4*)&tmp[8];
  }
}

// ---------------------------------------------------------------------------
// FUSED layer: aggregation (MFMA) + dense + LN + swish (+ pooled partial).
// Block = 32 output rows; 4 waves = {row-group g} x {j-half hf}.
// The full j range lives in the block, so num/den never hit global memory.
//   POOL=false: writes transposed bf16 hout[b][d][n]
//   POOL=true : writes partial[b][blk][DOUT] = sum_rows mask*act
// ---------------------------------------------------------------------------
template <int DIN, int DOUT, bool POOL>
__global__ __launch_bounds__(256, 2) void fused_layer(
    const float4* __restrict__ pnt, const ushort* __restrict__ hT,
    const float* __restrict__ W, const float* __restrict__ bias,
    const float* __restrict__ g, const float* __restrict__ be,
    ushort* __restrict__ hout, const float* __restrict__ mask,
    float* __restrict__ partial) {
  constexpr int NT = DIN / 16;
  constexpr int NO = DOUT / 64;
  constexpr int HALF = NPTS / 2;
  constexpr int TILES = HALF / 64;   // 16
  const int b = blockIdx.y;
  const int i0 = blockIdx.x * 32;
  const int tid = threadIdx.x;
  const int wv = tid >> 6, lane = tid & 63;
  const int gq = wv & 1;    // row group (16 rows)
  const int hf = wv >> 1;   // j half
  const int m = lane & 15, q = lane >> 4;
  const float4* pb = pnt + (size_t)b * NPTS;
  const ushort* hb = hT + (size_t)b * DIN * NPTS;

  __shared__ ushort sht[2][DIN][72];     // [half][d][j], pitch 72
  __shared__ float4 spnt[2][64];         // [half][swizzled j]
  __shared__ float snum[2][32][DIN];     // [half][row][d]
  __shared__ float sden[2][32];
  __shared__ float sinv[32];

  const float4 pi = pb[i0 + gq * 16 + m];   // my A-row's point

  f32x4 acc[NT];
#pragma unroll
  for (int nt = 0; nt < NT; nt++)
#pragma unroll
    for (int e = 0; e < 4; e++) acc[nt][e] = 0.f;
  float dacc = 0.f;

  const int sc = tid & 7;       // 16B chunk within 64-j row
  const int sd = tid >> 3;      // 0..31 d-row

  for (int t = 0; t < TILES; t++) {
    __syncthreads();
    // stage tile t of BOTH halves
#pragma unroll
    for (int h2 = 0; h2 < 2; h2++) {
      const int jb = h2 * HALF + t * 64;
#pragma unroll
      for (int dd = 0; dd < DIN; dd += 32) {
        const uint4 v = *(const uint4*)(hb + (size_t)(dd + sd) * NPTS + jb + sc * 8);
        *(uint4*)&sht[h2][dd + sd][sc * 8] = v;
      }
    }
    if (tid < 128) {
      const int h2 = tid >> 6, jj = tid & 63;
      spnt[h2][((jj & 7) << 3) | (jj >> 3)] = pb[h2 * HALF + t * 64 + jj];
    }
    __syncthreads();
#pragma unroll
    for (int s = 0; s < 2; s++) {
      short8 af;
#pragma unroll
      for (int jj = 0; jj < 8; jj++) {
        const float4 pj = spnt[hf][(jj << 3) | (s * 4 + q)];
        float arg = pi.w + pj.w;
        arg = fmaf(pi.x, pj.x, arg);
        arg = fmaf(pi.y, pj.y, arg);
        arg = fmaf(pi.z, pj.z, arg);
        const float w = __expf(arg);   // exp(-dist_ij)
        dacc += w;
        af[jj] = (short)f2bf(w);
      }
#pragma unroll
      for (int nt = 0; nt < NT; nt++) {
        const short8 bfr = *(const short8*)&sht[hf][nt * 16 + m][s * 32 + q * 8];
        acc[nt] = __builtin_amdgcn_mfma_f32_16x16x32_bf16(af, bfr, acc[nt], 0, 0, 0);
      }
    }
  }
  __syncthreads();   // all waves done reading sht/spnt

  // ---- combine split-K partials in LDS ----
  dacc += __shfl_xor(dacc, 16, 64);
  dacc += __shfl_xor(dacc, 32, 64);
  if (q == 0) sden[hf][gq * 16 + m] = dacc;
  // C/D layout: col = lane&15 (d within tile), row = quad*4 + reg
#pragma unroll
  for (int nt = 0; nt < NT; nt++)
#pragma unroll
    for (int r = 0; r < 4; r++)
      snum[hf][gq * 16 + q * 4 + r][nt * 16 + m] = acc[nt][r];
  __syncthreads();
  if (tid < 32) sinv[tid] = 1.0f / (sden[0][tid] + sden[1][tid]);
  __syncthreads();
  float* srow = (float*)sht;   // 32 x DIN, aliases dead sht
  {
    const float* n0 = &snum[0][0][0];
    const float* n1 = &snum[1][0][0];
    for (int idx = tid; idx < 32 * DIN; idx += 256)
      srow[idx] = (n0[idx] + n1[idx]) * sinv[idx / DIN];
  }
  __syncthreads();

  // ---- dense: wave wv handles local rows wv*8 .. wv*8+7 ----
  float o[8][NO];
#pragma unroll
  for (int e = 0; e < NO; e++) {
    const float bv = bias[lane + 64 * e];
#pragma unroll
    for (int r = 0; r < 8; r++) o[r][e] = bv;
  }
  for (int k = 0; k < DIN; k++) {
    float wreg[NO];
#pragma unroll
    for (int e = 0; e < NO; e++) wreg[e] = W[(size_t)k * DOUT + lane + 64 * e];
#pragma unroll
    for (int r = 0; r < 8; r++) {
      const float hr = srow[(wv * 8 + r) * DIN + k];
#pragma unroll
      for (int e = 0; e < NO; e++) o[r][e] = fmaf(hr, wreg[e], o[r][e]);
    }
  }

  // ---- LN + swish + output ----
  ushort* lt = (ushort*)snum;        // [32][DOUT], aliases dead snum
  float* sp = (float*)snum;          // [4][DOUT] for POOL
  float pacc[NO];
  if (POOL) {
#pragma unroll
    for (int e = 0; e < NO; e++) pacc[e] = 0.f;
  }
#pragma unroll
  for (int r = 0; r < 8; r++) {
    float m1 = 0.f, m2 = 0.f;
#pragma unroll
    for (int e = 0; e < NO; e++) { m1 += o[r][e]; m2 += o[r][e] * o[r][e]; }
#pragma unroll
    for (int off = 32; off > 0; off >>= 1) {
      m1 += __shfl_xor(m1, off, 64);
      m2 += __shfl_xor(m2, off, 64);
    }
    const float mu = m1 / DOUT;
    const float var = m2 / DOUT - mu * mu;
    const float rstd = rsqrtf(var + 1e-6f);
    float mval = 0.f;
    if (POOL) mval = mask[(size_t)b * NPTS + i0 + wv * 8 + r];
#pragma unroll
    for (int e = 0; e < NO; e++) {
      const int dco = lane + 64 * e;
      const float v = (o[r][e] - mu) * rstd * g[dco] + be[dco];
      const float act = v / (1.0f + __expf(-v));
      if (POOL) pacc[e] = fmaf(act, mval, pacc[e]);
      else lt[(wv * 8 + r) * DOUT + dco] = f2bf(act);
    }
  }
  if (POOL) {
#pragma unroll
    for (int e = 0; e < NO; e++) sp[wv * DOUT + lane + 64 * e] = pacc[e];
    __syncthreads();
    if (tid < DOUT) {
      const float s = (sp[0 * DOUT + tid] + sp[1 * DOUT + tid]) +
                      (sp[2 * DOUT + tid] + sp[3 * DOUT + tid]);
      partial[((size_t)b * (NPTS / 32) + blockIdx.x) * DOUT + tid] = s;
    }
  } else {
    __syncthreads();
    if (tid < DOUT) {
      ushort tmp[32];
#pragma unroll
      for (int r = 0; r < 32; r++) tmp[r] = lt[r * DOUT + tid];
      ushort* dst = hout + ((size_t)b * DOUT + tid) * NPTS + i0;
#pragma unroll
      for (int c = 0; c < 4; c++)
        *(uint4*)(dst + c * 8) = *(uint4*)&tmp[c * 8];
    }
  }
}

// ---------------------------------------------------------------------------
// readout: reduce 64 partial rows per batch, divide by count, Dense(256->128)
// ---------------------------------------------------------------------------
__global__ __launch_bounds__(256) void readout_kernel(
    const float* __restrict__ partial, const float* __restrict__ mask,
    const float* __restrict__ Wz, const float* __restrict__ bz,
    float* __restrict__ out) {
  const int b = blockIdx.x;
  const int tid = threadIdx.x;
  const float* pb = partial + (size_t)b * (NPTS / 32) * 256;
  float s0 = 0.f, s1 = 0.f, s2 = 0.f, s3 = 0.f;
#pragma unroll 4
  for (int p = 0; p < NPTS / 32; p += 4) {
    s0 += pb[(size_t)(p + 0) * 256 + tid];
    s1 += pb[(size_t)(p + 1) * 256 + tid];
    s2 += pb[(size_t)(p + 2) * 256 + tid];
    s3 += pb[(size_t)(p + 3) * 256 + tid];
  }
  const float s = (s0 + s1) + (s2 + s3);
  const float* mb = mask + (size_t)b * NPTS;
  float c = 0.f;
  for (int n = tid; n < NPTS; n += 256) c += mb[n];
  __shared__ float red[256];
  red[tid] = c;
  __syncthreads();
  for (int off = 128; off > 0; off >>= 1) {
    if (tid < off) red[tid] += red[tid + off];
    __syncthreads();
  }
  const float cnt = fmaxf(red[0], 1.0f);
  __shared__ float gf[256];
  gf[tid] = s / cnt;
  __syncthreads();
  if (tid < LATENT) {
    float z = bz[tid];
#pragma unroll 4
    for (int d = 0; d < 256; d++) z += gf[d] * Wz[(size_t)d * LATENT + tid];
    out[(size_t)b * LATENT + tid] = z;
  }
}

// ---------------------------------------------------------------------------
extern "C" void kernel_launch(void* const* d_in, const int* in_sizes, int n_in,
                              void* d_out, int out_size, void* d_ws, size_t ws_size,
                              hipStream_t stream) {
  const float* x    = (const float*)d_in[0];
  const float* mask = (const float*)d_in[1];
  const float* W0   = (const float*)d_in[2];
  const float* b0   = (const float*)d_in[3];
  const float* g0   = (const float*)d_in[4];
  const float* be0  = (const float*)d_in[5];
  const float* W1   = (const float*)d_in[6];
  const float* b1   = (const float*)d_in[7];
  const float* g1   = (const float*)d_in[8];
  const float* be1  = (const float*)d_in[9];
  const float* W2   = (const float*)d_in[10];
  const float* b2   = (const float*)d_in[11];
  const float* g2   = (const float*)d_in[12];
  const float* be2  = (const float*)d_in[13];
  const float* Wz   = (const float*)d_in[14];
  const float* bz   = (const float*)d_in[15];
  float* out = (float*)d_out;

  // workspace layout (bytes, 16B-aligned regions)
  char* ws = (char*)d_ws;
  float4* pnt     = (float4*)(ws);             // 8*2048*16        =  262144 B
  float*  hagg0   = (float*)(ws + 262144);     // 8*2048*3*4       =  196608 B
  ushort* h1T     = (ushort*)(ws + 458752);    // 8*64*2048*2      = 2097152 B
  ushort* h2T     = (ushort*)(ws + 2555904);   // 8*128*2048*2     = 4194304 B
  float*  partial = (float*)(ws + 6750208);    // 8*64*256*4       =  524288 B
  // total ~7.3 MB

  prep_kernel<<<dim3(BATCH), dim3(256), 0, stream>>>(x, mask, pnt);

  // layer 0: h = xc (D=3), VALU fp32
  agg3_kernel<<<dim3(NPTS / 64, BATCH), dim3(256), 0, stream>>>(pnt, hagg0);
  mlp0_kernel<<<dim3(BATCH * NPTS / 16), dim3(256), 0, stream>>>(
      hagg0, W0, b0, g0, be0, h1T);

  // layer 1 (64 -> 128): fused MFMA agg + dense + LN + swish
  fused_layer<64, 128, false><<<dim3(NPTS / 32, BATCH), dim3(256), 0, stream>>>(
      pnt, h1T, W1, b1, g1, be1, h2T, nullptr, nullptr);

  // layer 2 (128 -> 256): fused + masked-sum pooling
  fused_layer<128, 256, true><<<dim3(NPTS / 32, BATCH), dim3(256), 0, stream>>>(
      pnt, h2T, W2, b2, g2, be2, nullptr, mask, partial);

  // readout
  readout_kernel<<<dim3(BATCH), dim3(256), 0, stream>>>(partial, mask, Wz, bz, out);
}